// Round 2
// baseline (847.555 us; speedup 1.0000x reference)
//
#include <hip/hip_runtime.h>

#define B_ 2048
#define T_ 2048
#define SPW 16   // samples (batch rows) per wave
#define LDK 72   // f16 stride per sample row in LDS (144 B -> 16B-aligned reads)

typedef _Float16 f16x8 __attribute__((ext_vector_type(8)));
typedef float    f32x4 __attribute__((ext_vector_type(4)));
typedef unsigned u32x2 __attribute__((ext_vector_type(2)));

__device__ __forceinline__ unsigned pkrtz(float lo, float hi) {
    return __builtin_bit_cast(unsigned, __builtin_amdgcn_cvt_pkrtz(lo, hi));
}

// Batched MFMA RNN: one wave owns 16 samples; per step the 64x64 matvec for
// all 16 samples is 8x mfma_f32_16x16x32_f16 (4 M-tiles x 2 K-chunks).
// h state lives in LDS as f16 [sample][k] (stride LDK); the C->B layout
// transpose is the LDS round-trip. DS ops are in-order within a wave and the
// block is a single wave, so no barriers in the loop.
// Layout facts used:
//  - C/D: col = lane&15 (sample), row = 4*(lane>>4) + reg  [m89-verified]
//  - A/B: lane&15 = M-row / N-col, (lane>>4, elem j) -> k. Any consistent
//    (g,j)->k bijection is correct since A and B are packed with the SAME
//    convention (the k-contraction is symmetric) -- only C layout matters.
__global__ __launch_bounds__(64)
void rnn_mfma16(
    const float* __restrict__ x, const float* __restrict__ W_ih,
    const float* __restrict__ W_hh, const float* __restrict__ b_ih,
    const float* __restrict__ b_hh, const float* __restrict__ W_fc,
    const float* __restrict__ b_fc, float* __restrict__ out)
{
    __shared__ __align__(16) _Float16 hl[SPW * LDK];

    const int l = threadIdx.x;
    const int s = l & 15;            // sample column (N / C-col / A-row index)
    const int g = l >> 4;            // k-group selector & C row-quad selector
    const int sb = blockIdx.x * SPW; // first sample of this wave
    const float L2E2 = 2.8853900817779268f;  // 2*log2(e), folded into W/bias

    // ---- A-frags: W_hh rows 16m..16m+15, k = 32c + 8g + j, scaled by 2log2e.
    f16x8 a[2][4];
#pragma unroll
    for (int c = 0; c < 2; ++c)
#pragma unroll
        for (int m = 0; m < 4; ++m) {
            f16x8 v;
#pragma unroll
            for (int j = 0; j < 8; ++j)
                v[j] = (_Float16)(W_hh[(16 * m + s) * 64 + 32 * c + 8 * g + j] * L2E2);
            a[c][m] = v;
        }

    // ---- per-lane C-slot constants: rows 16m + 4g + r
    float wih[4][4], bw[4][4];
#pragma unroll
    for (int m = 0; m < 4; ++m)
#pragma unroll
        for (int r = 0; r < 4; ++r) {
            const int row = 16 * m + 4 * g + r;
            wih[m][r] = W_ih[row] * L2E2;
            bw[m][r]  = (b_ih[row] + b_hh[row]) * L2E2;
        }

    // ---- h0 = 0
    for (int i = l; i < SPW * LDK; i += 64) hl[i] = (_Float16)0.0f;
    __syncthreads();

    // Loop-invariant LDS pointers.
    // reads:  B-frag chunk c: k = 32c + 8g + j  (16B-aligned, b128)
    // writes: C quad of tile m: k = 16m + 4g + r (8B-aligned, b64)
    const _Float16* const rdp = &hl[s * LDK + 8 * g];
    _Float16* const       wrp = &hl[s * LDK + 4 * g];

    const float* xs = x + (size_t)(sb + s) * T_;
    float xr = xs[0];
    float h[4][4];

    for (int t = 0; t < T_; ++t) {
        // --- B operands: previous h (step 0: zeros) ---
        const f16x8 b0 = *(const f16x8*)(rdp);        // k =  0..31 slice
        const f16x8 b1 = *(const f16x8*)(rdp + 32);   // k = 32..63 slice

        // --- x prefetch for t+1 (independent of recurrence) ---
        const int tn = t + 1;
        const float xn = xs[tn < T_ ? tn : 0];

        // --- acc init (bias + x*w_ih as MFMA C-in) + 8 MFMA ---
        f32x4 acc[4];
#pragma unroll
        for (int m = 0; m < 4; ++m) {
            f32x4 ci;
#pragma unroll
            for (int r = 0; r < 4; ++r) ci[r] = fmaf(xr, wih[m][r], bw[m][r]);
            f32x4 p0 = __builtin_amdgcn_mfma_f32_16x16x32_f16(a[0][m], b0, ci, 0, 0, 0);
            acc[m]   = __builtin_amdgcn_mfma_f32_16x16x32_f16(a[1][m], b1, p0, 0, 0, 0);
        }

        // --- tanh (exp2 form; scale folded) + pack + writeback per tile ---
#pragma unroll
        for (int m = 0; m < 4; ++m) {
#pragma unroll
            for (int r = 0; r < 4; ++r) {
                const float e = __builtin_amdgcn_exp2f(acc[m][r]);
                h[m][r] = fmaf(-2.0f, __builtin_amdgcn_rcpf(e + 1.0f), 1.0f);
            }
            u32x2 w;
            w.x = pkrtz(h[m][0], h[m][1]);
            w.y = pkrtz(h[m][2], h[m][3]);
            *(u32x2*)(wrp + 16 * m) = w;
        }
        // Pin next iteration's ds_reads after this iteration's ds_writes at IR
        // level (cross-lane dependency the per-thread alias analysis can't see).
        asm volatile("" ::: "memory");
        xr = xn;
    }

    // ---- FC head: out[s] = sum_row h[row][s] * W_fc[row] + b_fc ----
    float p = 0.0f;
#pragma unroll
    for (int m = 0; m < 4; ++m)
#pragma unroll
        for (int r = 0; r < 4; ++r)
            p = fmaf(h[m][r], W_fc[16 * m + 4 * g + r], p);
    p += __shfl_down(p, 32);
    p += __shfl_down(p, 16);
    if (l < 16) out[sb + l] = p + b_fc[0];
}

extern "C" void kernel_launch(void* const* d_in, const int* in_sizes, int n_in,
                              void* d_out, int out_size, void* d_ws, size_t ws_size,
                              hipStream_t stream) {
    const float* x    = (const float*)d_in[0];
    const float* W_ih = (const float*)d_in[1];
    const float* W_hh = (const float*)d_in[2];
    const float* b_ih = (const float*)d_in[3];
    const float* b_hh = (const float*)d_in[4];
    const float* W_fc = (const float*)d_in[5];
    const float* b_fc = (const float*)d_in[6];
    float* out = (float*)d_out;

    rnn_mfma16<<<dim3(B_ / SPW), dim3(64), 0, stream>>>(x, W_ih, W_hh, b_ih, b_hh,
                                                        W_fc, b_fc, out);
}

// Round 3
// 692.724 us; speedup vs baseline: 1.2235x; 1.2235x over previous
//
#include <hip/hip_runtime.h>

#define B_ 2048
#define T_ 2048
#define SPW 16   // samples (batch rows) per wave

typedef _Float16 f16x8 __attribute__((ext_vector_type(8)));
typedef float    f32x4 __attribute__((ext_vector_type(4)));
typedef unsigned u32x4 __attribute__((ext_vector_type(4)));

__device__ __forceinline__ unsigned pkrtz(float lo, float hi) {
    return __builtin_bit_cast(unsigned, __builtin_amdgcn_cvt_pkrtz(lo, hi));
}

// Register-resident MFMA RNN (round 3): the round-2 LDS transpose is replaced
// by a k-relabeling. MFMA pairs A-slot (g,j) with B-slot (g,j); any bijection
// sigma(g,j)->k is valid if A and B use the SAME sigma (round 2's PASS
// verifies the A/B slot pairing on HW). Choose
//     sigma_c(g,j) = 16*(2c + (j>>2)) + 4g + (j&3)
// so that the B-fragment for step t+1 is exactly the lane's OWN C-output
// values from step t (C layout, m89-verified: col=lane&15, row=4*(lane>>4)+reg):
//     B chunk c, slot j  =  h[tile 2c+(j>>2)][reg j&3]   -- already in regs.
// Per step: 8 pkrtz -> 8 chained MFMA -> 16x tanh -> repeat. No LDS, no
// barriers, no cross-lane ops in the loop.
__global__ __launch_bounds__(64)
void rnn_mfma_reg(
    const float* __restrict__ x, const float* __restrict__ W_ih,
    const float* __restrict__ W_hh, const float* __restrict__ b_ih,
    const float* __restrict__ b_hh, const float* __restrict__ W_fc,
    const float* __restrict__ b_fc, float* __restrict__ out)
{
    const int l = threadIdx.x;
    const int s = l & 15;            // sample column (C-col / A-M-row index)
    const int g = l >> 4;            // slot group; C row-quad selector
    const int sb = blockIdx.x * SPW; // first sample of this wave
    const float L2E2 = 2.8853900817779268f;  // 2*log2(e), folded into W/bias

    // ---- A-frags: tile m covers W_hh rows 16m+u (u=lane&15); slot (g,j) of
    // chunk c holds k = sigma_c(g,j) = 16*(2c+(j>>2)) + 4g + (j&3).
    f16x8 a[2][4];
#pragma unroll
    for (int c = 0; c < 2; ++c)
#pragma unroll
        for (int m = 0; m < 4; ++m) {
            f16x8 v;
#pragma unroll
            for (int j = 0; j < 8; ++j) {
                const int k = 16 * (2 * c + (j >> 2)) + 4 * g + (j & 3);
                v[j] = (_Float16)(W_hh[(16 * m + s) * 64 + k] * L2E2);
            }
            a[c][m] = v;
        }

    // ---- per-lane C-slot constants: rows 16m + 4g + r
    float wih[4][4], bw[4][4];
#pragma unroll
    for (int m = 0; m < 4; ++m)
#pragma unroll
        for (int r = 0; r < 4; ++r) {
            const int row = 16 * m + 4 * g + r;
            wih[m][r] = W_ih[row] * L2E2;
            bw[m][r]  = (b_ih[row] + b_hh[row]) * L2E2;
        }

    // ---- state: h[m][r] = h_state[16m+4g+r] for sample s. h0 = 0.
    float h[4][4];
#pragma unroll
    for (int m = 0; m < 4; ++m)
#pragma unroll
        for (int r = 0; r < 4; ++r) h[m][r] = 0.0f;

    const float* xs = x + (size_t)(sb + s) * T_;
    float4 xq = *(const float4*)xs;  // covers t..t+3

    for (int t0 = 0; t0 < T_; t0 += 4) {
        // Prefetch next 4 timesteps (4-step slack hides L2/HBM latency).
        const float4 xn = *(const float4*)(t0 + 4 < T_ ? xs + t0 + 4 : xs);
        const float xa[4] = {xq.x, xq.y, xq.z, xq.w};

#pragma unroll
        for (int j4 = 0; j4 < 4; ++j4) {
            const float xr = xa[j4];

            // --- B frags from the lane's OWN h (sigma relabeling) ---
            const u32x4 q0 = {pkrtz(h[0][0], h[0][1]), pkrtz(h[0][2], h[0][3]),
                              pkrtz(h[1][0], h[1][1]), pkrtz(h[1][2], h[1][3])};
            const u32x4 q1 = {pkrtz(h[2][0], h[2][1]), pkrtz(h[2][2], h[2][3]),
                              pkrtz(h[3][0], h[3][1]), pkrtz(h[3][2], h[3][3])};
            const f16x8 b0 = __builtin_bit_cast(f16x8, q0);  // k = 0..31
            const f16x8 b1 = __builtin_bit_cast(f16x8, q1);  // k = 32..63

            // --- acc init (bias + x*w_ih as MFMA C-in) + 8 chained MFMA ---
            f32x4 acc[4];
#pragma unroll
            for (int m = 0; m < 4; ++m) {
                f32x4 ci;
#pragma unroll
                for (int r = 0; r < 4; ++r) ci[r] = fmaf(xr, wih[m][r], bw[m][r]);
                const f32x4 p0 =
                    __builtin_amdgcn_mfma_f32_16x16x32_f16(a[0][m], b0, ci, 0, 0, 0);
                acc[m] =
                    __builtin_amdgcn_mfma_f32_16x16x32_f16(a[1][m], b1, p0, 0, 0, 0);
            }

            // --- tanh(pre) = 1 - 2/(exp2(2log2e*pre)+1) ---
#pragma unroll
            for (int m = 0; m < 4; ++m)
#pragma unroll
                for (int r = 0; r < 4; ++r) {
                    const float e = __builtin_amdgcn_exp2f(acc[m][r]);
                    h[m][r] = fmaf(-2.0f, __builtin_amdgcn_rcpf(e + 1.0f), 1.0f);
                }
        }
        xq = xn;
    }

    // ---- FC head: out[s] = sum_row h[row][s] * W_fc[row] + b_fc ----
    float p = 0.0f;
#pragma unroll
    for (int m = 0; m < 4; ++m)
#pragma unroll
        for (int r = 0; r < 4; ++r)
            p = fmaf(h[m][r], W_fc[16 * m + 4 * g + r], p);
    p += __shfl_down(p, 32);  // g0+g2, g1+g3
    p += __shfl_down(p, 16);  // all four quads
    if (l < 16) out[sb + l] = p + b_fc[0];
}

extern "C" void kernel_launch(void* const* d_in, const int* in_sizes, int n_in,
                              void* d_out, int out_size, void* d_ws, size_t ws_size,
                              hipStream_t stream) {
    const float* x    = (const float*)d_in[0];
    const float* W_ih = (const float*)d_in[1];
    const float* W_hh = (const float*)d_in[2];
    const float* b_ih = (const float*)d_in[3];
    const float* b_hh = (const float*)d_in[4];
    const float* W_fc = (const float*)d_in[5];
    const float* b_fc = (const float*)d_in[6];
    float* out = (float*)d_out;

    rnn_mfma_reg<<<dim3(B_ / SPW), dim3(64), 0, stream>>>(x, W_ih, W_hh, b_ih, b_hh,
                                                          W_fc, b_fc, out);
}

// Round 4
// 635.755 us; speedup vs baseline: 1.3331x; 1.0896x over previous
//
#include <hip/hip_runtime.h>

#define B_ 2048
#define T_ 2048
#define SPW 16    // samples (batch rows) per wave
#define HALF 1024 // timesteps resident in LDS per staging pass (64 KiB)

typedef _Float16 f16x8 __attribute__((ext_vector_type(8)));
typedef float    f32x4 __attribute__((ext_vector_type(4)));
typedef unsigned u32x4 __attribute__((ext_vector_type(4)));

__device__ __forceinline__ unsigned pkrtz(float lo, float hi) {
    return __builtin_bit_cast(unsigned, __builtin_amdgcn_cvt_pkrtz(lo, hi));
}

// Round 4: round-3's register-resident MFMA recurrence (math bit-identical),
// with the x feed moved to LDS so the recurrence loop contains ZERO global
// memory, plus issue-path restructuring:
//  - x staged per 1024-step half: [16 rows][1024] f32, 4-word-group XOR
//    swizzle (word = row*1024 + ((t & ~3) ^ ((row&7)<<2)) + (t&3)) ->
//    conflict-free b128 reads in the loop.
//  - ci = bias + x*w_ih hoisted per 4-step group (h-independent).
//  - B-pack split: q0 (tiles 0,1) -> chain-0 MFMAs -> q1 (tiles 2,3) ->
//    chain-1 MFMAs; tanh emitted tile-ordered so next step's q0 unblocks
//    before tiles 2,3 finish. Scheduling-only: values identical to r3.
// sigma relabeling (HW-verified by r3 PASS): sigma_c(g,j) = 16*(2c+(j>>2)) +
// 4g + (j&3); B-frag for step t+1 = lane's own C-output of step t.
__global__ __launch_bounds__(64)
__attribute__((amdgpu_waves_per_eu(1, 1)))
void rnn_mfma_lds(
    const float* __restrict__ x, const float* __restrict__ W_ih,
    const float* __restrict__ W_hh, const float* __restrict__ b_ih,
    const float* __restrict__ b_hh, const float* __restrict__ W_fc,
    const float* __restrict__ b_fc, float* __restrict__ out)
{
    __shared__ __align__(16) float xl[SPW * HALF];  // 64 KiB

    const int l = threadIdx.x;
    const int s = l & 15;            // sample column (C-col / A-M-row index)
    const int g = l >> 4;            // slot group; C row-quad selector
    const int sb = blockIdx.x * SPW; // first sample of this wave
    const float L2E2 = 2.8853900817779268f;  // 2*log2(e), folded into W/bias

    // ---- A-frags: tile m covers W_hh rows 16m+u; slot (g,j) of chunk c
    // holds k = sigma_c(g,j).
    f16x8 a[2][4];
#pragma unroll
    for (int c = 0; c < 2; ++c)
#pragma unroll
        for (int m = 0; m < 4; ++m) {
            f16x8 v;
#pragma unroll
            for (int j = 0; j < 8; ++j) {
                const int k = 16 * (2 * c + (j >> 2)) + 4 * g + (j & 3);
                v[j] = (_Float16)(W_hh[(16 * m + s) * 64 + k] * L2E2);
            }
            a[c][m] = v;
        }

    // ---- per-lane C-slot constants: rows 16m + 4g + r
    float wih[4][4], bw[4][4];
#pragma unroll
    for (int m = 0; m < 4; ++m)
#pragma unroll
        for (int r = 0; r < 4; ++r) {
            const int row = 16 * m + 4 * g + r;
            wih[m][r] = W_ih[row] * L2E2;
            bw[m][r]  = (b_ih[row] + b_hh[row]) * L2E2;
        }

    // ---- state: h[m][r] = h_state[16m+4g+r] for sample s. h0 = 0.
    float h[4][4];
#pragma unroll
    for (int m = 0; m < 4; ++m)
#pragma unroll
        for (int r = 0; r < 4; ++r) h[m][r] = 0.0f;

    const float* xg = x + (size_t)sb * T_;  // this wave's 16 rows
    const int xbase = s << 10;              // word base of sample row
    const int sxr   = (s & 7) << 2;         // read-side swizzle

    for (int half = 0; half < 2; ++half) {
        // ---- stage 16 rows x 1024 cols (coalesced dwordx4, swizzled store)
        for (int it = l; it < SPW * (HALF / 4); it += 64) {
            const int row = it >> 8;   // uniform across the wave per iter
            const int c4  = it & 255;
            const float4 v =
                *(const float4*)(xg + (size_t)row * T_ + half * HALF + 4 * c4);
            const int w0 = (row << 10) + ((4 * c4) ^ ((row & 7) << 2));
            *(float4*)&xl[w0] = v;
        }
        __syncthreads();  // single wave: waitcnt + cheap barrier

        float4 xq = *(const float4*)&xl[xbase + (0 ^ sxr)];

        for (int t0 = 0; t0 < HALF; t0 += 4) {
            // next 4-step group (wraps to stale data on the last iter; the
            // dangling value is discarded -- xq is re-read after restaging).
            const int tn = (t0 + 4) & (HALF - 1);
            const float4 xn = *(const float4*)&xl[xbase + (tn ^ sxr)];
            const float xa[4] = {xq.x, xq.y, xq.z, xq.w};

            // --- hoisted affine: independent of h ---
            float ci[4][4][4];
#pragma unroll
            for (int j4 = 0; j4 < 4; ++j4)
#pragma unroll
                for (int m = 0; m < 4; ++m)
#pragma unroll
                    for (int r = 0; r < 4; ++r)
                        ci[j4][m][r] = fmaf(xa[j4], wih[m][r], bw[m][r]);

#pragma unroll
            for (int j4 = 0; j4 < 4; ++j4) {
                // --- B chunk 0 (tiles 0,1) -> chain-0 MFMAs ---
                const u32x4 q0 = {pkrtz(h[0][0], h[0][1]), pkrtz(h[0][2], h[0][3]),
                                  pkrtz(h[1][0], h[1][1]), pkrtz(h[1][2], h[1][3])};
                const f16x8 b0 = __builtin_bit_cast(f16x8, q0);
                f32x4 p0[4];
#pragma unroll
                for (int m = 0; m < 4; ++m)
                    p0[m] = __builtin_amdgcn_mfma_f32_16x16x32_f16(
                        a[0][m], b0, *(const f32x4*)ci[j4][m], 0, 0, 0);

                // --- B chunk 1 (tiles 2,3) -> chain-1 MFMAs ---
                const u32x4 q1 = {pkrtz(h[2][0], h[2][1]), pkrtz(h[2][2], h[2][3]),
                                  pkrtz(h[3][0], h[3][1]), pkrtz(h[3][2], h[3][3])};
                const f16x8 b1 = __builtin_bit_cast(f16x8, q1);
                f32x4 acc[4];
#pragma unroll
                for (int m = 0; m < 4; ++m)
                    acc[m] = __builtin_amdgcn_mfma_f32_16x16x32_f16(
                        a[1][m], b1, p0[m], 0, 0, 0);

                // --- tanh, tile-ordered (tiles 0,1 gate next step's q0) ---
#pragma unroll
                for (int m = 0; m < 4; ++m)
#pragma unroll
                    for (int r = 0; r < 4; ++r) {
                        const float e = __builtin_amdgcn_exp2f(acc[m][r]);
                        h[m][r] = fmaf(-2.0f, __builtin_amdgcn_rcpf(e + 1.0f), 1.0f);
                    }
            }
            xq = xn;
        }
    }

    // ---- FC head: out[s] = sum_row h[row][s] * W_fc[row] + b_fc ----
    float p = 0.0f;
#pragma unroll
    for (int m = 0; m < 4; ++m)
#pragma unroll
        for (int r = 0; r < 4; ++r)
            p = fmaf(h[m][r], W_fc[16 * m + 4 * g + r], p);
    p += __shfl_down(p, 32);
    p += __shfl_down(p, 16);
    if (l < 16) out[sb + l] = p + b_fc[0];
}

extern "C" void kernel_launch(void* const* d_in, const int* in_sizes, int n_in,
                              void* d_out, int out_size, void* d_ws, size_t ws_size,
                              hipStream_t stream) {
    const float* x    = (const float*)d_in[0];
    const float* W_ih = (const float*)d_in[1];
    const float* W_hh = (const float*)d_in[2];
    const float* b_ih = (const float*)d_in[3];
    const float* b_hh = (const float*)d_in[4];
    const float* W_fc = (const float*)d_in[5];
    const float* b_fc = (const float*)d_in[6];
    float* out = (float*)d_out;

    rnn_mfma_lds<<<dim3(B_ / SPW), dim3(64), 0, stream>>>(x, W_ih, W_hh, b_ih, b_hh,
                                                          W_fc, b_fc, out);
}

// Round 5
// 379.789 us; speedup vs baseline: 2.2316x; 1.6740x over previous
//
#include <hip/hip_runtime.h>

#define B_ 2048
#define T_ 2048
#define SPW 16    // samples per block (MFMA N dimension)
#define GSTR 162  // per-g word stride in exchange buf (16 samples * 10 + 2 pad)

typedef _Float16 f16x8 __attribute__((ext_vector_type(8)));
typedef float    f32x4 __attribute__((ext_vector_type(4)));
typedef unsigned u32x2 __attribute__((ext_vector_type(2)));
typedef unsigned u32x4 __attribute__((ext_vector_type(4)));

__device__ __forceinline__ unsigned pkrtz(float lo, float hi) {
    return __builtin_bit_cast(unsigned, __builtin_amdgcn_cvt_pkrtz(lo, hi));
}

// Round 5: 4-wave cooperative MFMA RNN. Round 4 proved the lone wave's SIMD
// is ~78% issue-busy with trans (tanh) = 512 of 744 cyc/step (quarter-rate
// transcendentals), while 3 of 4 SIMDs per CU idle. Split the 64 hidden rows
// across 4 waves (wave w = tile w = rows 16w..16w+15): tanh per wave drops
// 32->8 trans (128 cyc). sigma-relabeling (HW-verified r3/r4) makes the
// h-exchange LANE-ALIGNED: consumer lane (s,g) chunk c reads producer lane
// (s,g) of waves 2c,2c+1 -> 1 ds_write_b64 + 4 ds_read_b64 per step, no
// transpose. Double-buffered exchange -> ONE barrier per step (write of
// h_{t+1} targets the other buffer; read->tanh->write dependence orders the
// rest). Stride-10 words per sample + 2-word per-g pad => <=2-way bank
// aliasing (free).
__global__ __launch_bounds__(256)
void rnn_mfma_4w(
    const float* __restrict__ x, const float* __restrict__ W_ih,
    const float* __restrict__ W_hh, const float* __restrict__ b_ih,
    const float* __restrict__ b_hh, const float* __restrict__ W_fc,
    const float* __restrict__ b_fc, float* __restrict__ out)
{
    __shared__ __align__(16) unsigned ex[2][4 * GSTR];  // [buf][g][s][10 words]
    __shared__ float fcb[4][SPW];

    const int tid = threadIdx.x;
    const int w = tid >> 6;          // wave index == tile index (rows 16w+..)
    const int l = tid & 63;
    const int s = l & 15;            // sample column (C-col / A-M-row / B-N)
    const int g = l >> 4;            // slot group; C row-quad selector
    const int sb = blockIdx.x * SPW;
    const float L2E2 = 2.8853900817779268f;  // 2*log2(e), folded into W/bias

    // ---- A-frags for tile w: slot (g,j) of chunk c holds
    // k = sigma_c(g,j) = 16*(2c+(j>>2)) + 4g + (j&3).
    f16x8 a0, a1;
#pragma unroll
    for (int j = 0; j < 8; ++j) {
        const int k0 = 16 * (0 + (j >> 2)) + 4 * g + (j & 3);
        const int k1 = 16 * (2 + (j >> 2)) + 4 * g + (j & 3);
        a0[j] = (_Float16)(W_hh[(16 * w + s) * 64 + k0] * L2E2);
        a1[j] = (_Float16)(W_hh[(16 * w + s) * 64 + k1] * L2E2);
    }

    // ---- per-lane C-slot constants: rows 16w + 4g + r
    float wih[4], bw[4];
#pragma unroll
    for (int r = 0; r < 4; ++r) {
        const int row = 16 * w + 4 * g + r;
        wih[r] = W_ih[row] * L2E2;
        bw[r]  = (b_ih[row] + b_hh[row]) * L2E2;
    }

    // ---- exchange addresses (word granularity) ----
    const int exbase = g * GSTR + s * 10;  // this lane's sample slot
    unsigned* const wr0 = &ex[0][exbase + 2 * w];
    unsigned* const wr1 = &ex[1][exbase + 2 * w];
    const unsigned* const rd0 = &ex[0][exbase];
    const unsigned* const rd1 = &ex[1][exbase];

    // ---- state: h[r] = h_state[16w+4g+r] for sample s; h0 = 0.
    float h[4] = {0.0f, 0.0f, 0.0f, 0.0f};

    const float* xs = x + (size_t)(sb + s) * T_;
    float4 xq = *(const float4*)xs;

    for (int t0 = 0; t0 < T_; t0 += 4) {
        const float4 xn = *(const float4*)(xs + (t0 + 4 < T_ ? t0 + 4 : 0));
        const float xa[4] = {xq.x, xq.y, xq.z, xq.w};

#pragma unroll
        for (int j4 = 0; j4 < 4; ++j4) {
            const int buf = (t0 + j4) & 1;

            // --- publish this tile's 4 h values (f16-packed, 8B store) ---
            const u32x2 pk = {pkrtz(h[0], h[1]), pkrtz(h[2], h[3])};
            *(u32x2*)(buf ? wr1 : wr0) = pk;
            __syncthreads();  // all tiles' h_t visible

            // --- rebuild full B operands (lane-aligned: same (g,s) slot) ---
            const unsigned* rp = buf ? rd1 : rd0;
            const u32x2 e0 = *(const u32x2*)(rp + 0);  // tile 0 pair
            const u32x2 e1 = *(const u32x2*)(rp + 2);  // tile 1 pair
            const u32x2 e2 = *(const u32x2*)(rp + 4);  // tile 2 pair
            const u32x2 e3 = *(const u32x2*)(rp + 6);  // tile 3 pair
            const u32x4 q0 = {e0.x, e0.y, e1.x, e1.y};
            const u32x4 q1 = {e2.x, e2.y, e3.x, e3.y};
            const f16x8 b0 = __builtin_bit_cast(f16x8, q0);  // k =  0..31
            const f16x8 b1 = __builtin_bit_cast(f16x8, q1);  // k = 32..63

            // --- acc init (bias + x*w_ih as MFMA C-in) + 2 chained MFMA ---
            f32x4 ci;
#pragma unroll
            for (int r = 0; r < 4; ++r) ci[r] = fmaf(xa[j4], wih[r], bw[r]);
            const f32x4 p0 = __builtin_amdgcn_mfma_f32_16x16x32_f16(a0, b0, ci, 0, 0, 0);
            const f32x4 acc = __builtin_amdgcn_mfma_f32_16x16x32_f16(a1, b1, p0, 0, 0, 0);

            // --- tanh(pre) = 1 - 2/(exp2(2log2e*pre)+1): 8 trans total ---
#pragma unroll
            for (int r = 0; r < 4; ++r) {
                const float e = __builtin_amdgcn_exp2f(acc[r]);
                h[r] = fmaf(-2.0f, __builtin_amdgcn_rcpf(e + 1.0f), 1.0f);
            }
        }
        xq = xn;
    }

    // ---- FC head: out[s] = sum_row h[row][s] * W_fc[row] + b_fc ----
    float p = 0.0f;
#pragma unroll
    for (int r = 0; r < 4; ++r) p = fmaf(h[r], W_fc[16 * w + 4 * g + r], p);
    p += __shfl_down(p, 32);
    p += __shfl_down(p, 16);
    if (l < 16) fcb[w][l] = p;
    __syncthreads();
    if (tid < 16)
        out[sb + tid] = (fcb[0][tid] + fcb[1][tid]) + (fcb[2][tid] + fcb[3][tid]) + b_fc[0];
}

extern "C" void kernel_launch(void* const* d_in, const int* in_sizes, int n_in,
                              void* d_out, int out_size, void* d_ws, size_t ws_size,
                              hipStream_t stream) {
    const float* x    = (const float*)d_in[0];
    const float* W_ih = (const float*)d_in[1];
    const float* W_hh = (const float*)d_in[2];
    const float* b_ih = (const float*)d_in[3];
    const float* b_hh = (const float*)d_in[4];
    const float* W_fc = (const float*)d_in[5];
    const float* b_fc = (const float*)d_in[6];
    float* out = (float*)d_out;

    rnn_mfma_4w<<<dim3(B_ / SPW), dim3(256), 0, stream>>>(x, W_ih, W_hh, b_ih, b_hh,
                                                          W_fc, b_fc, out);
}